// Round 3
// baseline (429.969 us; speedup 1.0000x reference)
//
#include <hip/hip_runtime.h>
#include <hip/hip_bf16.h>
#include <stdint.h>

// NBEATS MoE block — round 3: routed top-2 grouped GEMM, zero-cost scheduling.
// Fixed-capacity expert segments (CAP=2304 rows = 18 tiles per expert, 6.5σ
// above the 2048 mean count) make segment starts compile-time constants:
//   - gate_cast_k assigns each row to its 2 expert slots directly via
//     global atomicAdd cursors (bit-stable: 2-term fp32 atomic sums are
//     order-independent), writing rowmap/wmap. No scheduler kernel.
//   - GEMM tile t -> expert t/18, rows t*128. Pad slots: rowmap/wmap are
//     memset to 0 (loads row 0, w==0 suppresses the final scatter).
//   gemm_k<GATHER,RELU,FINAL>: m97-style 128x128 tile, 4 waves, 4x4
//     mfma_f32_16x16x32_bf16, BK=32, global_load_lds width=16. GATHER
//     indirects A rows through rowmap (per-lane global addrs, free).
//     FINAL fuses gate-weight combine + scatter into split out via atomicAdd.

#define B_ROWS 8192
#define I_DIM  512
#define H_DIM  512
#define E_NUM  8
#define T_DIM  608
#define T_PAD  640
#define CAP    2304   // rows per expert segment (capacity)
#define TPE    18     // tiles per expert = CAP/128
#define NT     144    // total tiles = E_NUM*TPE
#define NPAD   18432  // NT*128

typedef unsigned short ushort_t;
typedef __attribute__((ext_vector_type(8))) __bf16 bf16x8;
typedef __attribute__((ext_vector_type(8))) unsigned short ushort8;
typedef __attribute__((ext_vector_type(4))) float floatx4;

__device__ __forceinline__ void gload_lds16(const void* g, void* l) {
  __builtin_amdgcn_global_load_lds(
      (const __attribute__((address_space(1))) unsigned int*)g,
      (__attribute__((address_space(3))) unsigned int*)l, 16, 0, 0);
}

__device__ __forceinline__ ushort_t f2bf(float v) {
  __hip_bfloat16 h = __float2bfloat16(v);
  return __builtin_bit_cast(unsigned short, h);
}

// ------------------------------------------------- gating + assignment ----
// one wave per row: LN (fp32) -> logits (8) -> top2 softmax -> direct slot
// assignment via atomic cursors; also casts x row to bf16.
__global__ __launch_bounds__(256) void gate_cast_k(
    const float* __restrict__ x, const float* __restrict__ gamma,
    const float* __restrict__ beta, const float* __restrict__ Wg,
    ushort_t* __restrict__ xb, int* __restrict__ rowmap,
    float* __restrict__ wmap, int* __restrict__ cursor)
{
  const int row  = (blockIdx.x * blockDim.x + threadIdx.x) >> 6;
  const int lane = threadIdx.x & 63;
  const float* xr = x + (size_t)row * I_DIM + lane * 8;
  float4 a = *(const float4*)(xr);
  float4 b = *(const float4*)(xr + 4);
  float xs[8] = {a.x, a.y, a.z, a.w, b.x, b.y, b.z, b.w};

  float s = 0.f;
#pragma unroll
  for (int j = 0; j < 8; ++j) s += xs[j];
#pragma unroll
  for (int off = 32; off; off >>= 1) s += __shfl_xor(s, off);
  const float mu = s * (1.0f / I_DIM);

  float vs = 0.f;
#pragma unroll
  for (int j = 0; j < 8; ++j) { float d = xs[j] - mu; vs += d * d; }
#pragma unroll
  for (int off = 32; off; off >>= 1) vs += __shfl_xor(vs, off);
  const float rstd = rsqrtf(vs * (1.0f / I_DIM) + 1e-5f);

  float lg[8] = {0.f, 0.f, 0.f, 0.f, 0.f, 0.f, 0.f, 0.f};
  const float* gmr = gamma + lane * 8;
  const float* btr = beta + lane * 8;
#pragma unroll
  for (int j = 0; j < 8; ++j) {
    const float y = (xs[j] - mu) * rstd * gmr[j] + btr[j];
    const float* wr = Wg + (size_t)(lane * 8 + j) * E_NUM;
#pragma unroll
    for (int e = 0; e < 8; ++e) lg[e] += y * wr[e];
  }
#pragma unroll
  for (int e = 0; e < 8; ++e)
#pragma unroll
    for (int off = 32; off; off >>= 1) lg[e] += __shfl_xor(lg[e], off);

  ushort8 o;
#pragma unroll
  for (int j = 0; j < 8; ++j) o[j] = f2bf(xs[j]);
  *(ushort8*)(xb + (size_t)row * I_DIM + lane * 8) = o;

  if (lane == 0) {
    int i0 = 0; float b0 = lg[0];
#pragma unroll
    for (int e = 1; e < 8; ++e) if (lg[e] > b0) { b0 = lg[e]; i0 = e; }
    int i1 = -1; float b1 = -3.4e38f;
#pragma unroll
    for (int e = 0; e < 8; ++e) if (e != i0 && lg[e] > b1) { b1 = lg[e]; i1 = e; }
    const float w0 = 1.0f / (1.0f + __expf(b1 - b0));
    const int p0 = i0 * CAP + atomicAdd(&cursor[i0], 1);
    rowmap[p0] = row; wmap[p0] = w0;
    const int p1 = i1 * CAP + atomicAdd(&cursor[i1], 1);
    rowmap[p1] = row; wmap[p1] = 1.0f - w0;
  }
}

// ------------------------------------------------- weight transpose+cast ----
__global__ __launch_bounds__(256) void transpose_cast_k(
    const float* __restrict__ src, ushort_t* __restrict__ dst,
    int R, int C, size_t srcBStr, size_t dstBStr)
{
  __shared__ float tile[32][33];
  src += (size_t)blockIdx.z * srcBStr;
  dst += (size_t)blockIdx.z * dstBStr;
  const int c0 = blockIdx.x * 32, r0 = blockIdx.y * 32;
  const int tx = threadIdx.x, ty = threadIdx.y;
#pragma unroll
  for (int i = 0; i < 4; ++i)
    tile[ty + i * 8][tx] = src[(size_t)(r0 + ty + i * 8) * C + c0 + tx];
  __syncthreads();
#pragma unroll
  for (int i = 0; i < 4; ++i) {
    const int c = c0 + ty + i * 8;
    if (c < C) dst[(size_t)c * R + r0 + tx] = f2bf(tile[tx][ty + i * 8]);
  }
}

// ------------------------------------------------------------------ GEMM ----
// tile t=blockIdx.x -> expert t/TPE, gathered rows [t*128, t*128+128).
template <bool GATHER, bool RELU, bool FINAL>
__global__ __launch_bounds__(256) void gemm_k(
    const ushort_t* __restrict__ A,      // GATHER: xb [8192][K]; else z [NPAD][K]
    const ushort_t* __restrict__ B,      // bf16 [E][N][K]
    size_t bEStr,
    const int* __restrict__ rowmap, const float* __restrict__ wmap,
    ushort_t* __restrict__ Z,            // mid out [NPAD][H_DIM]
    float* __restrict__ out)             // final out (split)
{
  constexpr int K = 512;
  __shared__ ushort_t lA[128 * 32];
  __shared__ ushort_t lB[128 * 32];
  __shared__ float wrow[128];
  __shared__ int rrow[128];

  const int t = blockIdx.x;
  const int e = t / TPE;
  const int zr0 = t * 128;
  const int bn0 = blockIdx.y * 128;

  const int tid = threadIdx.x, wid = tid >> 6, lane = tid & 63;
  const int sr = wid * 16 + (lane >> 2);
  const int sc = (lane & 3) * 8;

  const ushort_t* Bb = B + (size_t)e * bEStr + (size_t)bn0 * K;
  const ushort_t* gb = Bb + (size_t)sr * K + sc;
  const ushort_t *ga0, *ga1;
  if (GATHER) {
    ga0 = A + (size_t)rowmap[zr0 + sr] * K + sc;
    ga1 = A + (size_t)rowmap[zr0 + sr + 64] * K + sc;
  } else {
    ga0 = A + (size_t)(zr0 + sr) * K + sc;
    ga1 = ga0 + (size_t)64 * K;
  }
  ushort_t* la = lA + wid * 512;
  ushort_t* lb = lB + wid * 512;

  floatx4 acc[4][4] = {};
  const int wm = (wid >> 1) * 64, wn = (wid & 1) * 64;
  const int fr = lane & 15, q = lane >> 4;

  for (int k0 = 0; k0 < K; k0 += 32) {
    gload_lds16(ga0 + k0, la);
    gload_lds16(ga1 + k0, la + 64 * 32);
    gload_lds16(gb + k0, lb);
    gload_lds16(gb + (size_t)64 * K + k0, lb + 64 * 32);
    __syncthreads();

    bf16x8 af[4], bfr[4];
#pragma unroll
    for (int mi = 0; mi < 4; ++mi)
      af[mi] = *(const bf16x8*)(lA + (wm + mi * 16 + fr) * 32 + q * 8);
#pragma unroll
    for (int ni = 0; ni < 4; ++ni)
      bfr[ni] = *(const bf16x8*)(lB + (wn + ni * 16 + fr) * 32 + q * 8);
#pragma unroll
    for (int mi = 0; mi < 4; ++mi)
#pragma unroll
      for (int ni = 0; ni < 4; ++ni)
        acc[mi][ni] = __builtin_amdgcn_mfma_f32_16x16x32_bf16(
            af[mi], bfr[ni], acc[mi][ni], 0, 0, 0);
    __syncthreads();
  }

  if (!FINAL) {
    // C/D layout: col = lane&15, row = (lane>>4)*4 + reg (m89-verified)
    ushort_t* Zb = Z + (size_t)zr0 * H_DIM + bn0;
#pragma unroll
    for (int mi = 0; mi < 4; ++mi)
#pragma unroll
      for (int r = 0; r < 4; ++r) {
        const int row = wm + mi * 16 + q * 4 + r;
        ushort_t* zr = Zb + (size_t)row * H_DIM + wn + fr;
#pragma unroll
        for (int ni = 0; ni < 4; ++ni) {
          float v = acc[mi][ni][r];
          if (RELU) v = fmaxf(v, 0.0f);
          zr[ni * 16] = f2bf(v);
        }
      }
  } else {
    if (tid < 128) {
      wrow[tid] = wmap[zr0 + tid];
      rrow[tid] = rowmap[zr0 + tid];
    }
    __syncthreads();
#pragma unroll
    for (int mi = 0; mi < 4; ++mi)
#pragma unroll
      for (int r = 0; r < 4; ++r) {
        const int row = wm + mi * 16 + q * 4 + r;
        const float w = wrow[row];
        if (w != 0.0f) {
          const size_t orig = rrow[row];
#pragma unroll
          for (int ni = 0; ni < 4; ++ni) {
            const int col = bn0 + wn + ni * 16 + fr;
            if (col < T_DIM) {
              const float v = acc[mi][ni][r] * w;
              float* dst = (col < I_DIM)
                  ? out + orig * I_DIM + col
                  : out + (size_t)B_ROWS * I_DIM + orig * (T_DIM - I_DIM) +
                        (col - I_DIM);
              atomicAdd(dst, v);
            }
          }
        }
      }
  }
}

// ---------------------------------------------------------------- launch ----
extern "C" void kernel_launch(void* const* d_in, const int* in_sizes, int n_in,
                              void* d_out, int out_size, void* d_ws,
                              size_t ws_size, hipStream_t stream) {
  const float* x     = (const float*)d_in[0];
  const float* gamma = (const float*)d_in[1];
  const float* beta  = (const float*)d_in[2];
  const float* Wg    = (const float*)d_in[3];
  const float* W0    = (const float*)d_in[4];
  const float* Wmid  = (const float*)d_in[5];
  const float* Wout  = (const float*)d_in[6];
  float* out = (float*)d_out;

  char* ws = (char*)d_ws;
  size_t off = 0;
  auto alloc = [&](size_t bytes) -> char* {
    char* p = ws + off;
    off += (bytes + 255) & ~(size_t)255;
    return p;
  };

  const size_t SQ = (size_t)H_DIM * H_DIM;
  ushort_t* xb    = (ushort_t*)alloc((size_t)B_ROWS * I_DIM * 2);
  ushort_t* W0t   = (ushort_t*)alloc((size_t)E_NUM * SQ * 2);
  ushort_t* Wmidt = (ushort_t*)alloc((size_t)3 * E_NUM * SQ * 2);
  ushort_t* Woutt = (ushort_t*)alloc((size_t)E_NUM * T_PAD * H_DIM * 2);
  int*   rmap   = (int*)alloc(NPAD * sizeof(int));
  float* wmap   = (float*)alloc(NPAD * sizeof(float));
  int*   cursor = (int*)alloc(E_NUM * sizeof(int));
  ushort_t* z0 = (ushort_t*)alloc((size_t)NPAD * H_DIM * 2);
  ushort_t* z1 = (ushort_t*)alloc((size_t)NPAD * H_DIM * 2);

  hipMemsetAsync(d_out, 0, (size_t)out_size * sizeof(float), stream);
  hipMemsetAsync(rmap, 0, NPAD * sizeof(int), stream);
  hipMemsetAsync(wmap, 0, NPAD * sizeof(float), stream);
  hipMemsetAsync(cursor, 0, E_NUM * sizeof(int), stream);

  gate_cast_k<<<dim3(B_ROWS / 4), 256, 0, stream>>>(x, gamma, beta, Wg, xb,
                                                    rmap, wmap, cursor);
  transpose_cast_k<<<dim3(16, 16, 8), dim3(32, 8), 0, stream>>>(
      W0, W0t, 512, 512, SQ, SQ);
  transpose_cast_k<<<dim3(16, 16, 24), dim3(32, 8), 0, stream>>>(
      Wmid, Wmidt, 512, 512, SQ, SQ);
  transpose_cast_k<<<dim3(19, 16, 8), dim3(32, 8), 0, stream>>>(
      Wout, Woutt, 512, 608, (size_t)512 * 608, (size_t)T_PAD * 512);

  const dim3 gmid(NT, H_DIM / 128);
  const dim3 gfin(NT, T_PAD / 128);
  // z0 = gather(x) @ W0   (no relu)
  gemm_k<true, false, false><<<gmid, 256, 0, stream>>>(
      xb, W0t, SQ, rmap, wmap, z0, nullptr);
  // z1 = relu(z0 @ Wmid[0])
  gemm_k<false, true, false><<<gmid, 256, 0, stream>>>(
      z0, Wmidt + 0 * E_NUM * SQ, SQ, rmap, wmap, z1, nullptr);
  // z0 = relu(z1 @ Wmid[1])
  gemm_k<false, true, false><<<gmid, 256, 0, stream>>>(
      z1, Wmidt + 1 * E_NUM * SQ, SQ, rmap, wmap, z0, nullptr);
  // z1 = relu(z0 @ Wmid[2])
  gemm_k<false, true, false><<<gmid, 256, 0, stream>>>(
      z0, Wmidt + 2 * E_NUM * SQ, SQ, rmap, wmap, z1, nullptr);
  // out += gate_w * (z1 @ Wout), scattered + split backcast/forecast
  gemm_k<false, false, true><<<gfin, 256, 0, stream>>>(
      z1, Woutt, (size_t)T_PAD * H_DIM, rmap, wmap, nullptr, out);
}

// Round 4
// 257.385 us; speedup vs baseline: 1.6705x; 1.6705x over previous
//
#include <hip/hip_runtime.h>
#include <hip/hip_bf16.h>
#include <stdint.h>

// NBEATS MoE block — round 4: routed top-2 grouped GEMM.
// Scheduling via fixed-capacity expert segments (CAP=2304 = 18 tiles/expert,
// 6.5 sigma above the 2048 mean count): segment starts are compile-time
// constants, tile t -> expert t/TPE, rows t*128.
//   gate_cast_k : LN -> logits -> top2 softmax; writes gidx/gw (NO atomics);
//                 casts x to bf16.
//   assign_k    : 32 blocks x 256 rows; per-block LDS ranking, then 8 global
//                 atomics/block (256 total, vs round 3's 16384 same-line
//                 atomics that cost 197us). Slot permutation is output-
//                 invariant, so block ordering nondeterminism is bit-stable.
//   gemm_k      : m97-style 128x128 tile, 4 waves, 4x4 mfma 16x16x32_bf16,
//                 BK=32, global_load_lds width=16. Early-exits fully-pad
//                 tiles using the on-device counts. FINAL fuses gate combine
//                 + scatter into split backcast/forecast via atomicAdd.

#define B_ROWS 8192
#define I_DIM  512
#define H_DIM  512
#define E_NUM  8
#define T_DIM  608
#define T_PAD  640
#define CAP    2304   // rows per expert segment (capacity)
#define TPE    18     // tiles per expert = CAP/128
#define NT     144    // total tiles = E_NUM*TPE
#define NPAD   18432  // NT*128

typedef unsigned short ushort_t;
typedef __attribute__((ext_vector_type(8))) __bf16 bf16x8;
typedef __attribute__((ext_vector_type(8))) unsigned short ushort8;
typedef __attribute__((ext_vector_type(4))) float floatx4;

__device__ __forceinline__ void gload_lds16(const void* g, void* l) {
  __builtin_amdgcn_global_load_lds(
      (const __attribute__((address_space(1))) unsigned int*)g,
      (__attribute__((address_space(3))) unsigned int*)l, 16, 0, 0);
}

__device__ __forceinline__ ushort_t f2bf(float v) {
  __hip_bfloat16 h = __float2bfloat16(v);
  return __builtin_bit_cast(unsigned short, h);
}

// ---------------------------------------------------------------- gating ----
// one wave per row: LN (fp32) -> logits (8) -> top2 softmax; cast x to bf16.
__global__ __launch_bounds__(256) void gate_cast_k(
    const float* __restrict__ x, const float* __restrict__ gamma,
    const float* __restrict__ beta, const float* __restrict__ Wg,
    ushort_t* __restrict__ xb, int2* __restrict__ gidx, float2* __restrict__ gw)
{
  const int row  = (blockIdx.x * blockDim.x + threadIdx.x) >> 6;
  const int lane = threadIdx.x & 63;
  const float* xr = x + (size_t)row * I_DIM + lane * 8;
  float4 a = *(const float4*)(xr);
  float4 b = *(const float4*)(xr + 4);
  float xs[8] = {a.x, a.y, a.z, a.w, b.x, b.y, b.z, b.w};

  float s = 0.f;
#pragma unroll
  for (int j = 0; j < 8; ++j) s += xs[j];
#pragma unroll
  for (int off = 32; off; off >>= 1) s += __shfl_xor(s, off);
  const float mu = s * (1.0f / I_DIM);

  float vs = 0.f;
#pragma unroll
  for (int j = 0; j < 8; ++j) { float d = xs[j] - mu; vs += d * d; }
#pragma unroll
  for (int off = 32; off; off >>= 1) vs += __shfl_xor(vs, off);
  const float rstd = rsqrtf(vs * (1.0f / I_DIM) + 1e-5f);

  float lg[8] = {0.f, 0.f, 0.f, 0.f, 0.f, 0.f, 0.f, 0.f};
  const float* gmr = gamma + lane * 8;
  const float* btr = beta + lane * 8;
#pragma unroll
  for (int j = 0; j < 8; ++j) {
    const float y = (xs[j] - mu) * rstd * gmr[j] + btr[j];
    const float* wr = Wg + (size_t)(lane * 8 + j) * E_NUM;
#pragma unroll
    for (int e = 0; e < 8; ++e) lg[e] += y * wr[e];
  }
#pragma unroll
  for (int e = 0; e < 8; ++e)
#pragma unroll
    for (int off = 32; off; off >>= 1) lg[e] += __shfl_xor(lg[e], off);

  ushort8 o;
#pragma unroll
  for (int j = 0; j < 8; ++j) o[j] = f2bf(xs[j]);
  *(ushort8*)(xb + (size_t)row * I_DIM + lane * 8) = o;

  if (lane == 0) {
    int i0 = 0; float b0 = lg[0];
#pragma unroll
    for (int e = 1; e < 8; ++e) if (lg[e] > b0) { b0 = lg[e]; i0 = e; }
    int i1 = -1; float b1 = -3.4e38f;
#pragma unroll
    for (int e = 0; e < 8; ++e) if (e != i0 && lg[e] > b1) { b1 = lg[e]; i1 = e; }
    const float w0 = 1.0f / (1.0f + __expf(b1 - b0));
    gidx[row] = make_int2(i0, i1);
    gw[row] = make_float2(w0, 1.0f - w0);
  }
}

// ------------------------------------------------------------ assignment ----
// 32 blocks x 256 threads, one row per thread. LDS rank + 8 global atomics
// per block. Slot order within a segment is nondeterministic but output-
// invariant (row math is slot-independent; final 2-term fp32 adds commute).
__global__ __launch_bounds__(256) void assign_k(
    const int2* __restrict__ gidx, const float2* __restrict__ gw,
    int* __restrict__ rowmap, float* __restrict__ wmap,
    int* __restrict__ cursor)
{
  __shared__ int lcnt[E_NUM];
  __shared__ int lbase[E_NUM];
  const int tid = threadIdx.x;
  const int row = blockIdx.x * 256 + tid;
  if (tid < E_NUM) lcnt[tid] = 0;
  __syncthreads();
  const int2 g = gidx[row];
  const float2 w = gw[row];
  const int r0 = atomicAdd(&lcnt[g.x], 1);
  const int r1 = atomicAdd(&lcnt[g.y], 1);
  __syncthreads();
  if (tid < E_NUM) lbase[tid] = atomicAdd(&cursor[tid], lcnt[tid]);
  __syncthreads();
  const int p0 = g.x * CAP + lbase[g.x] + r0;
  rowmap[p0] = row; wmap[p0] = w.x;
  const int p1 = g.y * CAP + lbase[g.y] + r1;
  rowmap[p1] = row; wmap[p1] = w.y;
}

// ------------------------------------------------- weight transpose+cast ----
__global__ __launch_bounds__(256) void transpose_cast_k(
    const float* __restrict__ src, ushort_t* __restrict__ dst,
    int R, int C, size_t srcBStr, size_t dstBStr)
{
  __shared__ float tile[32][33];
  src += (size_t)blockIdx.z * srcBStr;
  dst += (size_t)blockIdx.z * dstBStr;
  const int c0 = blockIdx.x * 32, r0 = blockIdx.y * 32;
  const int tx = threadIdx.x, ty = threadIdx.y;
#pragma unroll
  for (int i = 0; i < 4; ++i)
    tile[ty + i * 8][tx] = src[(size_t)(r0 + ty + i * 8) * C + c0 + tx];
  __syncthreads();
#pragma unroll
  for (int i = 0; i < 4; ++i) {
    const int c = c0 + ty + i * 8;
    if (c < C) dst[(size_t)c * R + r0 + tx] = f2bf(tile[tx][ty + i * 8]);
  }
}

// ------------------------------------------------------------------ GEMM ----
// tile t=blockIdx.x -> expert t/TPE, gathered rows [t*128, t*128+128).
// Fully-pad tiles (local row start >= live count) exit immediately.
template <bool GATHER, bool RELU, bool FINAL>
__global__ __launch_bounds__(256) void gemm_k(
    const ushort_t* __restrict__ A,      // GATHER: xb [8192][K]; else z [NPAD][K]
    const ushort_t* __restrict__ B,      // bf16 [E][N][K]
    size_t bEStr,
    const int* __restrict__ rowmap, const float* __restrict__ wmap,
    const int* __restrict__ cursor,      // live counts per expert
    ushort_t* __restrict__ Z,            // mid out [NPAD][H_DIM]
    float* __restrict__ out)             // final out (split)
{
  constexpr int K = 512;
  __shared__ ushort_t lA[128 * 32];
  __shared__ ushort_t lB[128 * 32];
  __shared__ float wrow[128];
  __shared__ int rrow[128];

  const int t = blockIdx.x;
  const int e = t / TPE;
  if ((t - e * TPE) * 128 >= cursor[e]) return;  // dead (all-pad) tile
  const int zr0 = t * 128;
  const int bn0 = blockIdx.y * 128;

  const int tid = threadIdx.x, wid = tid >> 6, lane = tid & 63;
  const int sr = wid * 16 + (lane >> 2);
  const int sc = (lane & 3) * 8;

  const ushort_t* Bb = B + (size_t)e * bEStr + (size_t)bn0 * K;
  const ushort_t* gb = Bb + (size_t)sr * K + sc;
  const ushort_t *ga0, *ga1;
  if (GATHER) {
    ga0 = A + (size_t)rowmap[zr0 + sr] * K + sc;
    ga1 = A + (size_t)rowmap[zr0 + sr + 64] * K + sc;
  } else {
    ga0 = A + (size_t)(zr0 + sr) * K + sc;
    ga1 = ga0 + (size_t)64 * K;
  }
  ushort_t* la = lA + wid * 512;
  ushort_t* lb = lB + wid * 512;

  floatx4 acc[4][4] = {};
  const int wm = (wid >> 1) * 64, wn = (wid & 1) * 64;
  const int fr = lane & 15, q = lane >> 4;

  for (int k0 = 0; k0 < K; k0 += 32) {
    gload_lds16(ga0 + k0, la);
    gload_lds16(ga1 + k0, la + 64 * 32);
    gload_lds16(gb + k0, lb);
    gload_lds16(gb + (size_t)64 * K + k0, lb + 64 * 32);
    __syncthreads();

    bf16x8 af[4], bfr[4];
#pragma unroll
    for (int mi = 0; mi < 4; ++mi)
      af[mi] = *(const bf16x8*)(lA + (wm + mi * 16 + fr) * 32 + q * 8);
#pragma unroll
    for (int ni = 0; ni < 4; ++ni)
      bfr[ni] = *(const bf16x8*)(lB + (wn + ni * 16 + fr) * 32 + q * 8);
#pragma unroll
    for (int mi = 0; mi < 4; ++mi)
#pragma unroll
      for (int ni = 0; ni < 4; ++ni)
        acc[mi][ni] = __builtin_amdgcn_mfma_f32_16x16x32_bf16(
            af[mi], bfr[ni], acc[mi][ni], 0, 0, 0);
    __syncthreads();
  }

  if (!FINAL) {
    // C/D layout: col = lane&15, row = (lane>>4)*4 + reg (m89-verified)
    ushort_t* Zb = Z + (size_t)zr0 * H_DIM + bn0;
#pragma unroll
    for (int mi = 0; mi < 4; ++mi)
#pragma unroll
      for (int r = 0; r < 4; ++r) {
        const int row = wm + mi * 16 + q * 4 + r;
        ushort_t* zr = Zb + (size_t)row * H_DIM + wn + fr;
#pragma unroll
        for (int ni = 0; ni < 4; ++ni) {
          float v = acc[mi][ni][r];
          if (RELU) v = fmaxf(v, 0.0f);
          zr[ni * 16] = f2bf(v);
        }
      }
  } else {
    if (tid < 128) {
      wrow[tid] = wmap[zr0 + tid];
      rrow[tid] = rowmap[zr0 + tid];
    }
    __syncthreads();
#pragma unroll
    for (int mi = 0; mi < 4; ++mi)
#pragma unroll
      for (int r = 0; r < 4; ++r) {
        const int row = wm + mi * 16 + q * 4 + r;
        const float w = wrow[row];
        if (w != 0.0f) {
          const size_t orig = rrow[row];
#pragma unroll
          for (int ni = 0; ni < 4; ++ni) {
            const int col = bn0 + wn + ni * 16 + fr;
            if (col < T_DIM) {
              const float v = acc[mi][ni][r] * w;
              float* dst = (col < I_DIM)
                  ? out + orig * I_DIM + col
                  : out + (size_t)B_ROWS * I_DIM + orig * (T_DIM - I_DIM) +
                        (col - I_DIM);
              atomicAdd(dst, v);
            }
          }
        }
      }
  }
}

// ---------------------------------------------------------------- launch ----
extern "C" void kernel_launch(void* const* d_in, const int* in_sizes, int n_in,
                              void* d_out, int out_size, void* d_ws,
                              size_t ws_size, hipStream_t stream) {
  const float* x     = (const float*)d_in[0];
  const float* gamma = (const float*)d_in[1];
  const float* beta  = (const float*)d_in[2];
  const float* Wg    = (const float*)d_in[3];
  const float* W0    = (const float*)d_in[4];
  const float* Wmid  = (const float*)d_in[5];
  const float* Wout  = (const float*)d_in[6];
  float* out = (float*)d_out;

  char* ws = (char*)d_ws;
  size_t off = 0;
  auto alloc = [&](size_t bytes) -> char* {
    char* p = ws + off;
    off += (bytes + 255) & ~(size_t)255;
    return p;
  };

  const size_t SQ = (size_t)H_DIM * H_DIM;
  ushort_t* xb    = (ushort_t*)alloc((size_t)B_ROWS * I_DIM * 2);
  ushort_t* W0t   = (ushort_t*)alloc((size_t)E_NUM * SQ * 2);
  ushort_t* Wmidt = (ushort_t*)alloc((size_t)3 * E_NUM * SQ * 2);
  ushort_t* Woutt = (ushort_t*)alloc((size_t)E_NUM * T_PAD * H_DIM * 2);
  int2*   gidx  = (int2*)alloc((size_t)B_ROWS * sizeof(int2));
  float2* gwv   = (float2*)alloc((size_t)B_ROWS * sizeof(float2));
  int*   rmap   = (int*)alloc(NPAD * sizeof(int));
  float* wmap   = (float*)alloc(NPAD * sizeof(float));
  int*   cursor = (int*)alloc(E_NUM * sizeof(int));
  ushort_t* z0 = (ushort_t*)alloc((size_t)NPAD * H_DIM * 2);
  ushort_t* z1 = (ushort_t*)alloc((size_t)NPAD * H_DIM * 2);

  hipMemsetAsync(d_out, 0, (size_t)out_size * sizeof(float), stream);
  hipMemsetAsync(rmap, 0, NPAD * sizeof(int), stream);
  hipMemsetAsync(wmap, 0, NPAD * sizeof(float), stream);
  hipMemsetAsync(cursor, 0, E_NUM * sizeof(int), stream);

  gate_cast_k<<<dim3(B_ROWS / 4), 256, 0, stream>>>(x, gamma, beta, Wg, xb,
                                                    gidx, gwv);
  transpose_cast_k<<<dim3(16, 16, 8), dim3(32, 8), 0, stream>>>(
      W0, W0t, 512, 512, SQ, SQ);
  transpose_cast_k<<<dim3(16, 16, 24), dim3(32, 8), 0, stream>>>(
      Wmid, Wmidt, 512, 512, SQ, SQ);
  transpose_cast_k<<<dim3(19, 16, 8), dim3(32, 8), 0, stream>>>(
      Wout, Woutt, 512, 608, (size_t)512 * 608, (size_t)T_PAD * 512);
  assign_k<<<dim3(B_ROWS / 256), 256, 0, stream>>>(gidx, gwv, rmap, wmap,
                                                   cursor);

  const dim3 gmid(NT, H_DIM / 128);
  const dim3 gfin(NT, T_PAD / 128);
  // z0 = gather(x) @ W0   (no relu)
  gemm_k<true, false, false><<<gmid, 256, 0, stream>>>(
      xb, W0t, SQ, rmap, wmap, cursor, z0, nullptr);
  // z1 = relu(z0 @ Wmid[0])
  gemm_k<false, true, false><<<gmid, 256, 0, stream>>>(
      z0, Wmidt + 0 * E_NUM * SQ, SQ, rmap, wmap, cursor, z1, nullptr);
  // z0 = relu(z1 @ Wmid[1])
  gemm_k<false, true, false><<<gmid, 256, 0, stream>>>(
      z1, Wmidt + 1 * E_NUM * SQ, SQ, rmap, wmap, cursor, z0, nullptr);
  // z1 = relu(z0 @ Wmid[2])
  gemm_k<false, true, false><<<gmid, 256, 0, stream>>>(
      z0, Wmidt + 2 * E_NUM * SQ, SQ, rmap, wmap, cursor, z1, nullptr);
  // out += gate_w * (z1 @ Wout), scattered + split backcast/forecast
  gemm_k<false, false, true><<<gfin, 256, 0, stream>>>(
      z1, Woutt, (size_t)T_PAD * H_DIM, rmap, wmap, cursor, nullptr, out);
}